// Round 9
// baseline (128.247 us; speedup 1.0000x reference)
//
#include <hip/hip_runtime.h>
#include <hip/hip_bf16.h>
#include <stdint.h>

#define NNODES  1000000
#define INDIM   128
#define HIDDIM  256
#define NCLSN   47
#define N0SZ    1171456
#define N1SZ    45056
#define N2SZ    4096
#define F0SZ    25
#define F1SZ    10

typedef __attribute__((ext_vector_type(8))) short short8;
typedef __attribute__((ext_vector_type(4))) float f32x4;

__device__ inline unsigned short f2bfu(float x) {
    union { __hip_bfloat16 h; unsigned short u; } cv;
    cv.h = __float2bfloat16(x);
    return cv.u;
}

__device__ inline float bfu2f(unsigned short u) {
    union { float f; unsigned int u; } cv;
    cv.u = ((unsigned int)u) << 16;
    return cv.f;
}

// ---------------------------------------------------------------------------
// Kernel 0: init live-row structures. mask[i]=(i<4096); list[0..4096)=i;
// nlive=4096.
// ---------------------------------------------------------------------------
__global__ __launch_bounds__(256) void init_kernel(
    int* __restrict__ mask, int* __restrict__ list, int* __restrict__ nlive) {
    const int tid = blockIdx.x * 256 + threadIdx.x;
    if (tid < N1SZ) mask[tid] = (tid < N2SZ) ? 1 : 0;
    if (tid < N2SZ) list[tid] = tid;
    if (tid == 0) *nlive = N2SZ;
}

// ---------------------------------------------------------------------------
// Kernel 1: dedup-append H rows referenced by layer-1 neighbors.
// List order nondeterministic; per-row outputs order-independent -> exact.
// ---------------------------------------------------------------------------
__global__ __launch_bounds__(256) void mark_kernel(
    const int* __restrict__ col1, int* __restrict__ mask,
    int* __restrict__ list, int* __restrict__ nlive) {
    const int t = blockIdx.x * 256 + threadIdx.x;
    if (t < N2SZ * F1SZ) {
        int c = col1[t];
        if (atomicExch(&mask[c], 1) == 0) {
            int k = atomicAdd(nlive, 1);
            list[k] = c;
        }
    }
}

// ---------------------------------------------------------------------------
// Kernel 2: prep — weight transpose to bf16 [N][K]; COMPACTED flat gather
// indices over live rows only: fidx_c[j*25+f] = gid0[col0[list[j]*25+f]],
// sidx_c[j] = gid0[list[j]].
// ---------------------------------------------------------------------------
__global__ __launch_bounds__(256) void prep_kernel(
    const float* __restrict__ Wn0, const float* __restrict__ Wr0,
    const float* __restrict__ Wn1, const float* __restrict__ Wr1,
    const int* __restrict__ gid0, const int* __restrict__ col0,
    const int* __restrict__ list, const int* __restrict__ nlive,
    __hip_bfloat16* __restrict__ W0T, __hip_bfloat16* __restrict__ W1T,
    int* __restrict__ fidx_c, int* __restrict__ sidx_c) {
    const int tid = blockIdx.x * 256 + threadIdx.x;
    if (tid < 256 * 256) {
        int n = tid >> 8, k = tid & 255;
        float v = (k < INDIM) ? Wn0[(size_t)k * HIDDIM + n] : Wr0[(size_t)(k - INDIM) * HIDDIM + n];
        W0T[(size_t)n * 256 + k] = __float2bfloat16(v);
    }
    if (tid < 48 * 512) {
        int n = tid / 512, k = tid % 512;
        float v = 0.f;
        if (n < NCLSN) v = (k < HIDDIM) ? Wn1[(size_t)k * NCLSN + n] : Wr1[(size_t)(k - HIDDIM) * NCLSN + n];
        W1T[(size_t)n * 512 + k] = __float2bfloat16(v);
    }
    const int nl = *nlive;
    if (tid < nl) sidx_c[tid] = gid0[list[tid]];
    if (tid < nl * F0SZ) {
        int j = tid / F0SZ, f = tid % F0SZ;
        fidx_c[tid] = gid0[col0[(size_t)list[j] * F0SZ + f]];
    }
}

// ---------------------------------------------------------------------------
// Kernel 3: FUSED layer 0 over COMPACTED live rows. 32 rows/block, 512 thr.
//   phase A: stage 800 compacted indices (dense, coalesced); gather 32x25
//            neighbor rows (fp32, 512B) + 32 self rows, register-accumulate;
//            mean; bf16; LDS A-tile [32][264pad].
//   phase B: 8-wave MFMA — wave w covers rows [(w>>2)*16,+16) x cols
//            [(w&3)*64,+64), K=256 vs W0T (L2-hot); +bias, ReLU ->
//            H rows at ORIGINAL indices.
// ---------------------------------------------------------------------------
__global__ __launch_bounds__(512) void fused_layer0_kernel(
    const float* __restrict__ node_feat, const int* __restrict__ fidx_c,
    const int* __restrict__ sidx_c, const int* __restrict__ list,
    const int* __restrict__ nlive, const __hip_bfloat16* __restrict__ W0T,
    const float* __restrict__ b0, __hip_bfloat16* __restrict__ H) {
    __shared__ int sg[32 * F0SZ];
    __shared__ int sself[32];
    __shared__ int slist[32];
    __shared__ alignas(16) short Atile[32 * 264];

    const int tid = threadIdx.x;
    const int rowbase = blockIdx.x * 32;
    const int nl = *nlive;
    if (rowbase >= nl) return;

    // ---- stage compacted indices (dense, coalesced) ----
    if (tid < 32) {
        int idx = rowbase + tid;
        slist[tid] = (idx < nl) ? list[idx] : -1;
        sself[tid] = (idx < nl) ? sidx_c[idx] : 0;
    }
    for (int t = tid; t < 32 * F0SZ; t += 512) {
        int e = rowbase * F0SZ + t;
        sg[t] = (e < nl * F0SZ) ? fidx_c[e] : 0;
    }
    __syncthreads();

    // ---- gather + mean: 32 rows x 16 lanes, each lane 8 dims ----
    {
        const int r = tid >> 4;        // 0..31
        const int l = tid & 15;        // 0..15, dims [l*8, l*8+8)
        const bool live = (slist[r] >= 0);
        float a0 = 0.f, a1 = 0.f, a2 = 0.f, a3 = 0.f, a4 = 0.f, a5 = 0.f, a6 = 0.f, a7 = 0.f;
        float4 s0 = make_float4(0.f, 0.f, 0.f, 0.f);
        float4 s1 = make_float4(0.f, 0.f, 0.f, 0.f);
        if (live) {
            #pragma unroll
            for (int f = 0; f < F0SZ; ++f) {
                const float* p = node_feat + (size_t)sg[r * F0SZ + f] * INDIM + l * 8;
                float4 v0 = ((const float4*)p)[0];
                float4 v1 = ((const float4*)p)[1];
                a0 += v0.x; a1 += v0.y; a2 += v0.z; a3 += v0.w;
                a4 += v1.x; a5 += v1.y; a6 += v1.z; a7 += v1.w;
            }
            const float* sp = node_feat + (size_t)sself[r] * INDIM + l * 8;
            s0 = ((const float4*)sp)[0];
            s1 = ((const float4*)sp)[1];
        }
        const float s = 1.0f / F0SZ;
        short8 m;
        m[0] = f2bfu(a0 * s); m[1] = f2bfu(a1 * s); m[2] = f2bfu(a2 * s); m[3] = f2bfu(a3 * s);
        m[4] = f2bfu(a4 * s); m[5] = f2bfu(a5 * s); m[6] = f2bfu(a6 * s); m[7] = f2bfu(a7 * s);
        *(short8*)&Atile[r * 264 + l * 8] = m;
        short8 se;
        se[0] = f2bfu(s0.x); se[1] = f2bfu(s0.y); se[2] = f2bfu(s0.z); se[3] = f2bfu(s0.w);
        se[4] = f2bfu(s1.x); se[5] = f2bfu(s1.y); se[6] = f2bfu(s1.z); se[7] = f2bfu(s1.w);
        *(short8*)&Atile[r * 264 + 128 + l * 8] = se;
    }
    __syncthreads();

    // ---- MFMA GEMM: wave w -> rows [(w>>2)*16,+16), cols [(w&3)*64,+64) ----
    {
        const int wid = tid >> 6;          // 0..7
        const int lane = tid & 63;
        const int l15 = lane & 15;
        const int g = lane >> 4;
        const int rhalf = (wid >> 2) * 16; // 0 or 16
        const int nbase = (wid & 3) * 64;
        const short* B = (const short*)W0T;
        f32x4 acc[4] = {};
        #pragma unroll
        for (int kk = 0; kk < 256; kk += 32) {
            const int ka = kk + g * 8;
            short8 a = *(const short8*)&Atile[(rhalf + l15) * 264 + ka];
            #pragma unroll
            for (int nt = 0; nt < 4; ++nt) {
                short8 b = *(const short8*)(B + (size_t)(nbase + nt * 16 + l15) * 256 + ka);
                acc[nt] = __builtin_amdgcn_mfma_f32_16x16x32_bf16(a, b, acc[nt], 0, 0, 0);
            }
        }
        #pragma unroll
        for (int nt = 0; nt < 4; ++nt) {
            const int col = nbase + nt * 16 + l15;
            const float bias = b0[col];
            #pragma unroll
            for (int r = 0; r < 4; ++r) {
                const int row = slist[rhalf + g * 4 + r];
                if (row >= 0) {
                    float v = acc[nt][r] + bias;
                    v = v > 0.f ? v : 0.f;
                    H[(size_t)row * HIDDIM + col] = __float2bfloat16(v);
                }
            }
        }
    }
}

// ---------------------------------------------------------------------------
// Kernel 4: FUSED layer 1 (unchanged). 512 thr/block, 16 dst rows/block.
// ---------------------------------------------------------------------------
__global__ __launch_bounds__(512) void fused_layer1_kernel(
    const __hip_bfloat16* __restrict__ H, const int* __restrict__ col1,
    const __hip_bfloat16* __restrict__ W1T, const float* __restrict__ b1,
    float* __restrict__ out) {
    __shared__ int sc[16 * F1SZ];
    __shared__ alignas(16) short Xtile[16 * 520];
    __shared__ alignas(16) float red[8][16 * 48];

    const int tid = threadIdx.x;
    const int rowbase = blockIdx.x * 16;

    if (tid < 16 * F1SZ) {
        int i = rowbase + tid / F1SZ;
        int f = tid % F1SZ;
        sc[tid] = col1[(size_t)i * F1SZ + f];
    }
    __syncthreads();

    {
        const int r = tid >> 5;
        const int l = tid & 31;
        const unsigned short* Hs = (const unsigned short*)H;
        float a0 = 0.f, a1 = 0.f, a2 = 0.f, a3 = 0.f, a4 = 0.f, a5 = 0.f, a6 = 0.f, a7 = 0.f;
        #pragma unroll
        for (int f = 0; f < F1SZ; ++f) {
            const unsigned short* p = Hs + (size_t)sc[r * F1SZ + f] * HIDDIM + l * 8;
            ushort4 v0 = ((const ushort4*)p)[0];
            ushort4 v1 = ((const ushort4*)p)[1];
            a0 += bfu2f(v0.x); a1 += bfu2f(v0.y); a2 += bfu2f(v0.z); a3 += bfu2f(v0.w);
            a4 += bfu2f(v1.x); a5 += bfu2f(v1.y); a6 += bfu2f(v1.z); a7 += bfu2f(v1.w);
        }
        const float s = 1.0f / F1SZ;
        short8 m;
        m[0] = f2bfu(a0 * s); m[1] = f2bfu(a1 * s); m[2] = f2bfu(a2 * s); m[3] = f2bfu(a3 * s);
        m[4] = f2bfu(a4 * s); m[5] = f2bfu(a5 * s); m[6] = f2bfu(a6 * s); m[7] = f2bfu(a7 * s);
        *(short8*)&Xtile[r * 520 + l * 8] = m;
        short8 se = *(const short8*)((const short*)Hs + (size_t)(rowbase + r) * HIDDIM + l * 8);
        *(short8*)&Xtile[r * 520 + 256 + l * 8] = se;
    }
    __syncthreads();

    {
        const int wid = tid >> 6;
        const int lane = tid & 63;
        const int l15 = lane & 15;
        const int g = lane >> 4;
        const short* B = (const short*)W1T;
        f32x4 acc[3] = {};
        const int kbase = wid * 64;
        #pragma unroll
        for (int ks = 0; ks < 2; ++ks) {
            const int ka = kbase + ks * 32 + g * 8;
            short8 a = *(const short8*)&Xtile[l15 * 520 + ka];
            #pragma unroll
            for (int nt = 0; nt < 3; ++nt) {
                short8 b = *(const short8*)(B + (size_t)(nt * 16 + l15) * 512 + ka);
                acc[nt] = __builtin_amdgcn_mfma_f32_16x16x32_bf16(a, b, acc[nt], 0, 0, 0);
            }
        }
        #pragma unroll
        for (int nt = 0; nt < 3; ++nt)
            #pragma unroll
            for (int rr = 0; rr < 4; ++rr)
                red[wid][(g * 4 + rr) * 48 + nt * 16 + l15] = acc[nt][rr];
    }
    __syncthreads();

    for (int t = tid; t < 16 * 48; t += 512) {
        int rr = t / 48, c = t % 48;
        if (c < NCLSN) {
            float v = b1[c];
            #pragma unroll
            for (int w = 0; w < 8; ++w) v += red[w][t];
            out[(size_t)(rowbase + rr) * NCLSN + c] = v;
        }
    }
}

// ---------------------------------------------------------------------------
extern "C" void kernel_launch(void* const* d_in, const int* in_sizes, int n_in,
                              void* d_out, int out_size, void* d_ws, size_t ws_size,
                              hipStream_t stream) {
    const float* node_feat = (const float*)d_in[0];
    const int*   gid0      = (const int*)d_in[1];
    const int*   col0      = (const int*)d_in[2];
    const int*   col1      = (const int*)d_in[3];
    const float* Wn0       = (const float*)d_in[4];
    const float* Wr0       = (const float*)d_in[5];
    const float* b0        = (const float*)d_in[6];
    const float* Wn1       = (const float*)d_in[7];
    const float* Wr1       = (const float*)d_in[8];
    const float* b1        = (const float*)d_in[9];

    char* ws = (char*)d_ws;
    // ws layout:
    //   H      bf16 [45056][256] : 23,068,672
    //   W0T    bf16 [256][256]   :    131,072   @ 23,068,672
    //   W1T    bf16 [48][512]    :     49,152   @ 23,199,744
    //   fidx_c int  [1,126,400]  :  4,505,600   @ 23,248,896
    //   sidx_c int  [45,056]     :    180,224   @ 27,754,496
    //   mask   int  [45,056]     :    180,224   @ 27,934,720
    //   list   int  [45,056]     :    180,224   @ 28,114,944
    //   nlive  int  [64]         :        256   @ 28,295,168
    __hip_bfloat16* H     = (__hip_bfloat16*)(ws);
    __hip_bfloat16* W0T   = (__hip_bfloat16*)(ws + 23068672);
    __hip_bfloat16* W1T   = (__hip_bfloat16*)(ws + 23199744);
    int*            fidx_c = (int*)(ws + 23248896);
    int*            sidx_c = (int*)(ws + 27754496);
    int*            mask   = (int*)(ws + 27934720);
    int*            list   = (int*)(ws + 28114944);
    int*            nlive  = (int*)(ws + 28295168);
    float* out = (float*)d_out;

    hipLaunchKernelGGL(init_kernel, dim3((N1SZ + 255) / 256), dim3(256), 0, stream,
                       mask, list, nlive);
    hipLaunchKernelGGL(mark_kernel, dim3((N2SZ * F1SZ + 255) / 256), dim3(256), 0, stream,
                       col1, mask, list, nlive);
    hipLaunchKernelGGL(prep_kernel, dim3(4400), dim3(256), 0, stream,
                       Wn0, Wr0, Wn1, Wr1, gid0, col0, list, nlive,
                       W0T, W1T, fidx_c, sidx_c);
    hipLaunchKernelGGL(fused_layer0_kernel, dim3((N1SZ + 31) / 32), dim3(512), 0, stream,
                       node_feat, fidx_c, sidx_c, list, nlive, W0T, b0, H);
    hipLaunchKernelGGL(fused_layer1_kernel, dim3(N2SZ / 16), dim3(512), 0, stream,
                       H, col1, W1T, b1, out);
}

// Round 10
// 111.408 us; speedup vs baseline: 1.1512x; 1.1512x over previous
//
#include <hip/hip_runtime.h>
#include <hip/hip_bf16.h>
#include <stdint.h>

#define NNODES  1000000
#define INDIM   128
#define HIDDIM  256
#define NCLSN   47
#define N0SZ    1171456
#define N1SZ    45056
#define N2SZ    4096
#define F0SZ    25
#define F1SZ    10

typedef __attribute__((ext_vector_type(8))) short short8;
typedef __attribute__((ext_vector_type(4))) float f32x4;

__device__ inline unsigned short f2bfu(float x) {
    union { __hip_bfloat16 h; unsigned short u; } cv;
    cv.h = __float2bfloat16(x);
    return cv.u;
}

__device__ inline float bfu2f(unsigned short u) {
    union { float f; unsigned int u; } cv;
    cv.u = ((unsigned int)u) << 16;
    return cv.f;
}

// ---------------------------------------------------------------------------
// Kernel 1: prep — weight transpose to bf16 [N][K]; flatten two-level gather
// indices (fidx[e] = gid0[col0[e]], sidx[i] = gid0[i]); seed live-row
// structures: mask[i]=(i<4096), list[0..4096)=identity, nlive=4096.
// (Full-width fidx: gid0 is L2-resident, col0 read coalesced — cheaper than
//  compacting, which round 9 proved a net loss.)
// ---------------------------------------------------------------------------
__global__ __launch_bounds__(256) void prep_kernel(
    const float* __restrict__ Wn0, const float* __restrict__ Wr0,
    const float* __restrict__ Wn1, const float* __restrict__ Wr1,
    const int* __restrict__ gid0, const int* __restrict__ col0,
    __hip_bfloat16* __restrict__ W0T, __hip_bfloat16* __restrict__ W1T,
    int* __restrict__ fidx, int* __restrict__ sidx,
    int* __restrict__ mask, int* __restrict__ list, int* __restrict__ nlive) {
    const int tid = blockIdx.x * 256 + threadIdx.x;
    if (tid < 256 * 256) {
        int n = tid >> 8, k = tid & 255;
        float v = (k < INDIM) ? Wn0[(size_t)k * HIDDIM + n] : Wr0[(size_t)(k - INDIM) * HIDDIM + n];
        W0T[(size_t)n * 256 + k] = __float2bfloat16(v);
    }
    if (tid < 48 * 512) {
        int n = tid / 512, k = tid % 512;
        float v = 0.f;
        if (n < NCLSN) v = (k < HIDDIM) ? Wn1[(size_t)k * NCLSN + n] : Wr1[(size_t)(k - HIDDIM) * NCLSN + n];
        W1T[(size_t)n * 512 + k] = __float2bfloat16(v);
    }
    if (tid < N1SZ) {
        sidx[tid] = gid0[tid];
        mask[tid] = (tid < N2SZ) ? 1 : 0;
    }
    if (tid < N2SZ) list[tid] = tid;
    if (tid == 0) *nlive = N2SZ;
    if (tid < N1SZ * F0SZ) fidx[tid] = gid0[col0[tid]];
}

// ---------------------------------------------------------------------------
// Kernel 1b: dedup-append H rows referenced by layer-1 neighbors.
// atomicExch on mask dedups; winner appends row id to list. List order is
// nondeterministic but per-row outputs are order-independent -> d_out exact.
// ---------------------------------------------------------------------------
__global__ __launch_bounds__(256) void mark_kernel(
    const int* __restrict__ col1, int* __restrict__ mask,
    int* __restrict__ list, int* __restrict__ nlive) {
    const int t = blockIdx.x * 256 + threadIdx.x;
    if (t < N2SZ * F1SZ) {
        int c = col1[t];
        if (atomicExch(&mask[c], 1) == 0) {
            int k = atomicAdd(nlive, 1);
            list[k] = c;
        }
    }
}

// ---------------------------------------------------------------------------
// Kernel 2: FUSED layer 0 over COMPACTED live rows.
// Per block: 16 live rows from list[rowbase..rowbase+16), 256 threads.
// (16-row/256-thr beats 32-row/512-thr: more independent blocks/CU for
//  latency hiding, smaller barrier straggler set — round-9 A/B evidence.)
// ---------------------------------------------------------------------------
__global__ __launch_bounds__(256) void fused_layer0_kernel(
    const float* __restrict__ node_feat, const int* __restrict__ fidx,
    const int* __restrict__ sidx, const int* __restrict__ list,
    const int* __restrict__ nlive, const __hip_bfloat16* __restrict__ W0T,
    const float* __restrict__ b0, __hip_bfloat16* __restrict__ H) {
    __shared__ int sg[16 * F0SZ];
    __shared__ int sself[16];
    __shared__ int slist[16];
    __shared__ alignas(16) short Atile[16 * 264];

    const int tid = threadIdx.x;
    const int rowbase = blockIdx.x * 16;
    const int nl = *nlive;
    if (rowbase >= nl) return;

    // ---- stage row ids + flat indices (list/fidx are L2-hot) ----
    if (tid < 16) {
        int idx = rowbase + tid;
        int row = (idx < nl) ? list[idx] : -1;
        slist[tid] = row;
        sself[tid] = (row >= 0) ? sidx[row] : 0;
    }
    for (int t = tid; t < 16 * F0SZ; t += 256) {
        int idx = rowbase + t / F0SZ;
        sg[t] = (idx < nl) ? fidx[(size_t)list[idx] * F0SZ + t % F0SZ] : 0;
    }
    __syncthreads();

    // ---- gather + mean: 16 rows x 16 lanes, each lane 8 dims ----
    {
        const int r = tid >> 4;        // 0..15
        const int l = tid & 15;        // 0..15, covers dims [l*8, l*8+8)
        const bool live = (slist[r] >= 0);
        float a0 = 0.f, a1 = 0.f, a2 = 0.f, a3 = 0.f, a4 = 0.f, a5 = 0.f, a6 = 0.f, a7 = 0.f;
        float4 s0 = make_float4(0.f, 0.f, 0.f, 0.f);
        float4 s1 = make_float4(0.f, 0.f, 0.f, 0.f);
        if (live) {
            #pragma unroll
            for (int f = 0; f < F0SZ; ++f) {
                const float* p = node_feat + (size_t)sg[r * F0SZ + f] * INDIM + l * 8;
                float4 v0 = ((const float4*)p)[0];
                float4 v1 = ((const float4*)p)[1];
                a0 += v0.x; a1 += v0.y; a2 += v0.z; a3 += v0.w;
                a4 += v1.x; a5 += v1.y; a6 += v1.z; a7 += v1.w;
            }
            const float* sp = node_feat + (size_t)sself[r] * INDIM + l * 8;
            s0 = ((const float4*)sp)[0];
            s1 = ((const float4*)sp)[1];
        }
        const float s = 1.0f / F0SZ;
        short8 m;
        m[0] = f2bfu(a0 * s); m[1] = f2bfu(a1 * s); m[2] = f2bfu(a2 * s); m[3] = f2bfu(a3 * s);
        m[4] = f2bfu(a4 * s); m[5] = f2bfu(a5 * s); m[6] = f2bfu(a6 * s); m[7] = f2bfu(a7 * s);
        *(short8*)&Atile[r * 264 + l * 8] = m;
        short8 se;
        se[0] = f2bfu(s0.x); se[1] = f2bfu(s0.y); se[2] = f2bfu(s0.z); se[3] = f2bfu(s0.w);
        se[4] = f2bfu(s1.x); se[5] = f2bfu(s1.y); se[6] = f2bfu(s1.z); se[7] = f2bfu(s1.w);
        *(short8*)&Atile[r * 264 + 128 + l * 8] = se;
    }
    __syncthreads();

    // ---- MFMA GEMM: wave w covers N cols [w*64, w*64+64) ----
    {
        const int wid = tid >> 6;
        const int lane = tid & 63;
        const int l15 = lane & 15;
        const int g = lane >> 4;
        const int nbase = wid * 64;
        const short* B = (const short*)W0T;
        f32x4 acc[4] = {};
        #pragma unroll
        for (int kk = 0; kk < 256; kk += 32) {
            const int ka = kk + g * 8;
            short8 a = *(const short8*)&Atile[l15 * 264 + ka];
            #pragma unroll
            for (int nt = 0; nt < 4; ++nt) {
                short8 b = *(const short8*)(B + (size_t)(nbase + nt * 16 + l15) * 256 + ka);
                acc[nt] = __builtin_amdgcn_mfma_f32_16x16x32_bf16(a, b, acc[nt], 0, 0, 0);
            }
        }
        #pragma unroll
        for (int nt = 0; nt < 4; ++nt) {
            const int col = nbase + nt * 16 + l15;
            const float bias = b0[col];
            #pragma unroll
            for (int r = 0; r < 4; ++r) {
                const int row = slist[g * 4 + r];
                if (row >= 0) {
                    float v = acc[nt][r] + bias;
                    v = v > 0.f ? v : 0.f;
                    H[(size_t)row * HIDDIM + col] = __float2bfloat16(v);
                }
            }
        }
    }
}

// ---------------------------------------------------------------------------
// Kernel 3: FUSED layer 1 (unchanged). 512 thr/block, 16 dst rows/block.
// ---------------------------------------------------------------------------
__global__ __launch_bounds__(512) void fused_layer1_kernel(
    const __hip_bfloat16* __restrict__ H, const int* __restrict__ col1,
    const __hip_bfloat16* __restrict__ W1T, const float* __restrict__ b1,
    float* __restrict__ out) {
    __shared__ int sc[16 * F1SZ];
    __shared__ alignas(16) short Xtile[16 * 520];
    __shared__ alignas(16) float red[8][16 * 48];

    const int tid = threadIdx.x;
    const int rowbase = blockIdx.x * 16;

    if (tid < 16 * F1SZ) {
        int i = rowbase + tid / F1SZ;
        int f = tid % F1SZ;
        sc[tid] = col1[(size_t)i * F1SZ + f];
    }
    __syncthreads();

    {
        const int r = tid >> 5;
        const int l = tid & 31;
        const unsigned short* Hs = (const unsigned short*)H;
        float a0 = 0.f, a1 = 0.f, a2 = 0.f, a3 = 0.f, a4 = 0.f, a5 = 0.f, a6 = 0.f, a7 = 0.f;
        #pragma unroll
        for (int f = 0; f < F1SZ; ++f) {
            const unsigned short* p = Hs + (size_t)sc[r * F1SZ + f] * HIDDIM + l * 8;
            ushort4 v0 = ((const ushort4*)p)[0];
            ushort4 v1 = ((const ushort4*)p)[1];
            a0 += bfu2f(v0.x); a1 += bfu2f(v0.y); a2 += bfu2f(v0.z); a3 += bfu2f(v0.w);
            a4 += bfu2f(v1.x); a5 += bfu2f(v1.y); a6 += bfu2f(v1.z); a7 += bfu2f(v1.w);
        }
        const float s = 1.0f / F1SZ;
        short8 m;
        m[0] = f2bfu(a0 * s); m[1] = f2bfu(a1 * s); m[2] = f2bfu(a2 * s); m[3] = f2bfu(a3 * s);
        m[4] = f2bfu(a4 * s); m[5] = f2bfu(a5 * s); m[6] = f2bfu(a6 * s); m[7] = f2bfu(a7 * s);
        *(short8*)&Xtile[r * 520 + l * 8] = m;
        short8 se = *(const short8*)((const short*)Hs + (size_t)(rowbase + r) * HIDDIM + l * 8);
        *(short8*)&Xtile[r * 520 + 256 + l * 8] = se;
    }
    __syncthreads();

    {
        const int wid = tid >> 6;
        const int lane = tid & 63;
        const int l15 = lane & 15;
        const int g = lane >> 4;
        const short* B = (const short*)W1T;
        f32x4 acc[3] = {};
        const int kbase = wid * 64;
        #pragma unroll
        for (int ks = 0; ks < 2; ++ks) {
            const int ka = kbase + ks * 32 + g * 8;
            short8 a = *(const short8*)&Xtile[l15 * 520 + ka];
            #pragma unroll
            for (int nt = 0; nt < 3; ++nt) {
                short8 b = *(const short8*)(B + (size_t)(nt * 16 + l15) * 512 + ka);
                acc[nt] = __builtin_amdgcn_mfma_f32_16x16x32_bf16(a, b, acc[nt], 0, 0, 0);
            }
        }
        #pragma unroll
        for (int nt = 0; nt < 3; ++nt)
            #pragma unroll
            for (int rr = 0; rr < 4; ++rr)
                red[wid][(g * 4 + rr) * 48 + nt * 16 + l15] = acc[nt][rr];
    }
    __syncthreads();

    for (int t = tid; t < 16 * 48; t += 512) {
        int rr = t / 48, c = t % 48;
        if (c < NCLSN) {
            float v = b1[c];
            #pragma unroll
            for (int w = 0; w < 8; ++w) v += red[w][t];
            out[(size_t)(rowbase + rr) * NCLSN + c] = v;
        }
    }
}

// ---------------------------------------------------------------------------
extern "C" void kernel_launch(void* const* d_in, const int* in_sizes, int n_in,
                              void* d_out, int out_size, void* d_ws, size_t ws_size,
                              hipStream_t stream) {
    const float* node_feat = (const float*)d_in[0];
    const int*   gid0      = (const int*)d_in[1];
    const int*   col0      = (const int*)d_in[2];
    const int*   col1      = (const int*)d_in[3];
    const float* Wn0       = (const float*)d_in[4];
    const float* Wr0       = (const float*)d_in[5];
    const float* b0        = (const float*)d_in[6];
    const float* Wn1       = (const float*)d_in[7];
    const float* Wr1       = (const float*)d_in[8];
    const float* b1        = (const float*)d_in[9];

    char* ws = (char*)d_ws;
    // ws layout:
    //   H     bf16 [45056][256] : 23,068,672
    //   W0T   bf16 [256][256]   :    131,072   @ 23,068,672
    //   W1T   bf16 [48][512]    :     49,152   @ 23,199,744
    //   fidx  int  [1,126,400]  :  4,505,600   @ 23,248,896
    //   sidx  int  [45,056]     :    180,224   @ 27,754,496
    //   mask  int  [45,056]     :    180,224   @ 27,934,720
    //   list  int  [45,056]     :    180,224   @ 28,114,944
    //   nlive int  [64]         :        256   @ 28,295,168
    __hip_bfloat16* H    = (__hip_bfloat16*)(ws);
    __hip_bfloat16* W0T  = (__hip_bfloat16*)(ws + 23068672);
    __hip_bfloat16* W1T  = (__hip_bfloat16*)(ws + 23199744);
    int*            fidx = (int*)(ws + 23248896);
    int*            sidx = (int*)(ws + 27754496);
    int*            mask = (int*)(ws + 27934720);
    int*            list = (int*)(ws + 28114944);
    int*            nlive= (int*)(ws + 28295168);
    float* out = (float*)d_out;

    hipLaunchKernelGGL(prep_kernel, dim3(4400), dim3(256), 0, stream,
                       Wn0, Wr0, Wn1, Wr1, gid0, col0, W0T, W1T, fidx, sidx,
                       mask, list, nlive);
    hipLaunchKernelGGL(mark_kernel, dim3((N2SZ * F1SZ + 255) / 256), dim3(256), 0, stream,
                       col1, mask, list, nlive);
    hipLaunchKernelGGL(fused_layer0_kernel, dim3(N1SZ / 16), dim3(256), 0, stream,
                       node_feat, fidx, sidx, list, nlive, W0T, b0, H);
    hipLaunchKernelGGL(fused_layer1_kernel, dim3(N2SZ / 16), dim3(512), 0, stream,
                       H, col1, W1T, b1, out);
}